// Round 7
// baseline (272.495 us; speedup 1.0000x reference)
//
#include <hip/hip_runtime.h>
#include <hip/hip_bf16.h>
#include <stdint.h>

// ---------------------------------------------------------------------------
// RG-LRU block: T=8192, D_MODEL=768, D_RNN=1024, KW=4.
// Round 12: conv barrier-cadence attack.  R5 evidence: conv at 882 TF = the
// ~900 TF ceiling of the 2-barrier-per-K-step structure (16 MFMA/wave per
// barrier-pair).  The 4 shift tiles of one kc read DISJOINT LDS -> no
// barriers between shifts.  New conv:
//  - per kc: stage 4 B shift tiles (32KB, dbuf) + 132-row halo (8.45KB,
//    single-buffered, prefetched post-barrier) -> 64 MFMA/wave per
//    barrier-pair (4x R5), counted vmcnt(8).
//  - LDS 72.3KB -> 2 blocks/CU kept (launch_bounds(256,2)).
//  - dense GEMMs / scans / prep byte-identical to R5.
// ---------------------------------------------------------------------------

#define T_LEN 8192
#define DM 768
#define DR 1024
#define NC 128   // scan chunks
#define CL 64    // chunk length

typedef __bf16 bf16x8 __attribute__((ext_vector_type(8)));
typedef float  f32x4  __attribute__((ext_vector_type(4)));

#define AS1 __attribute__((address_space(1)))
#define AS3 __attribute__((address_space(3)))

__device__ __forceinline__ void cp16_g2l(const void* g, void* l) {
    __builtin_amdgcn_global_load_lds((const AS1 void*)g, (AS3 void*)l, 16, 0, 0);
}

__device__ __forceinline__ float gelu_tanh(float x) {
    const float inner = 0.7978845608028654f * (x + 0.044715f * x * x * x);
    return 0.5f * x * (1.f + tanhf(inner));
}

__device__ __forceinline__ __bf16 f2b(float v) {
    __hip_bfloat16 h = __float2bfloat16(v);
    return *reinterpret_cast<__bf16*>(&h);
}

// ---------------------------------------------------------------------------
// Pipelined dense GEMM: C[m,n] = sum_k A[m,k]*B[n,k] (+bias[n]).
// BM=128, BK=32, 256 threads (4 waves, 2Mx2N), 4 blocks/CU.  K % 32 == 0.
// LDS rows are 32 elements = 4 16B chunks; chunk slot s at row r holds global
// chunk s ^ ((r>>1) & 3)  -> bank-balanced wave64 ds_read_b128.
// EPI: 0 = fp32 +bias (BN=64); 1 = bf16 +bias; 2 = split (gelu->Cv / D2).
// Epilogue reuses the 32KB smem arena for coalesced 16B stores.
// ---------------------------------------------------------------------------
template<int BN, int EPI, bool SHIFT>
__global__ __launch_bounds__(256, 4)
void gemm_mfma(const __hip_bfloat16* __restrict__ A,
               const __hip_bfloat16* __restrict__ B,
               const float* __restrict__ bias,
               void* __restrict__ Cv,
               int K, int lda, int N,
               __hip_bfloat16* __restrict__ D2)
{
    constexpr int NI  = BN / 32;           // n-frags per wave (4 or 2)
    constexpr int BLD = (BN * 4) / 256;    // B cp16 per thread (2 or 1)
    constexpr int NLD = 2 + BLD;           // cp16 per thread per tile
    __shared__ __align__(16) unsigned char smem[32768];
    __bf16* Asb = (__bf16*)smem;            // [2][128*32]
    __bf16* Bsb = (__bf16*)(smem + 16384);  // [2][BN*32]

    const int tid  = threadIdx.x;
    const int lane = tid & 63;
    const int wave = tid >> 6;
    const size_t m0 = (size_t)blockIdx.x * 128;
    const int    n0 = blockIdx.y * BN;
    const int wm = (wave >> 1) * 64;
    const int wn = (wave & 1) * (BN / 2);

    f32x4 acc[4][NI];
#pragma unroll
    for (int i = 0; i < 4; ++i)
#pragma unroll
        for (int j = 0; j < NI; ++j)
            acc[i][j] = f32x4{0.f, 0.f, 0.f, 0.f};

    const int frow = lane & 15;
    const int fq   = lane >> 4;             // chunk index 0..3 within 32-wide row

    auto stage = [&](int buf, int k0) {
        // A tile: 128 rows x 4 chunks = 512 chunks
#pragma unroll
        for (int q = 0; q < 2; ++q) {
            const int lin = q * 256 + tid;
            const int rr  = lin >> 2;
            const int gc  = (lin & 3) ^ ((rr >> 1) & 3);
            const size_t ar = m0 + rr + (SHIFT ? (size_t)(k0 >> 10) : 0);
            const int    ac = SHIFT ? (k0 & 1023) : k0;
            cp16_g2l(A + ar * (size_t)lda + ac + gc * 8, Asb + buf * 4096 + lin * 8);
        }
        // B tile: BN rows x 4 chunks
#pragma unroll
        for (int q = 0; q < BLD; ++q) {
            const int lin = q * 256 + tid;
            const int rr  = lin >> 2;
            const int gc  = (lin & 3) ^ ((rr >> 1) & 3);
            cp16_g2l(B + (size_t)(n0 + rr) * K + k0 + gc * 8,
                     Bsb + buf * (BN * 32) + lin * 8);
        }
    };

    const int nt = K / 32;
    stage(0, 0);
    int cur = 0;
    for (int t = 0; t < nt; ++t) {
        if (t + 1 < nt) {
            stage(cur ^ 1, (t + 1) * 32);
            // wait only for tile t (the NLD loads just issued stay in flight)
            asm volatile("s_waitcnt vmcnt(%0)" :: "n"(NLD) : "memory");
        } else {
            asm volatile("s_waitcnt vmcnt(0)" ::: "memory");
        }
        __builtin_amdgcn_sched_barrier(0);
        __builtin_amdgcn_s_barrier();          // buf[cur] staged for all waves
        __builtin_amdgcn_sched_barrier(0);

        bf16x8 af[4], bfr[NI];
#pragma unroll
        for (int mi = 0; mi < 4; ++mi) {
            const int R = wm + mi * 16 + frow;
            af[mi] = *(const bf16x8*)&Asb[cur * 4096 + R * 32 + ((fq ^ ((R >> 1) & 3)) * 8)];
        }
#pragma unroll
        for (int ni = 0; ni < NI; ++ni) {
            const int R = wn + ni * 16 + frow;
            bfr[ni] = *(const bf16x8*)&Bsb[cur * (BN * 32) + R * 32 + ((fq ^ ((R >> 1) & 3)) * 8)];
        }
        asm volatile("s_waitcnt lgkmcnt(0)" ::: "memory");  // my reads serviced
        __builtin_amdgcn_sched_barrier(0);
        __builtin_amdgcn_s_barrier();          // buf[cur] free for overwrite
        __builtin_amdgcn_sched_barrier(0);

        __builtin_amdgcn_s_setprio(1);
#pragma unroll
        for (int mi = 0; mi < 4; ++mi)
#pragma unroll
            for (int ni = 0; ni < NI; ++ni)
                acc[mi][ni] = __builtin_amdgcn_mfma_f32_16x16x32_bf16(
                    af[mi], bfr[ni], acc[mi][ni], 0, 0, 0);
        __builtin_amdgcn_s_setprio(0);
        cur ^= 1;
    }

    // ---- epilogue: acc -> swizzled LDS -> coalesced 16B/lane global stores.
    // C/D frag layout: col = lane&15, row = (lane>>4)*4 + reg.
    __syncthreads();
    const int er = fq * 4;
    const int ec = frow;

    if (EPI == 0) {
        // fp32 tile 128 x BN(=64): 32 KB = the whole arena.
        float* Cl = (float*)smem;
#pragma unroll
        for (int ni = 0; ni < NI; ++ni) {
            const int cc = wn + ni * 16 + ec;
            const float bv = bias ? bias[n0 + cc] : 0.f;
#pragma unroll
            for (int mi = 0; mi < 4; ++mi)
#pragma unroll
                for (int r2 = 0; r2 < 4; ++r2) {
                    const int R = wm + mi * 16 + er + r2;
                    Cl[R * 64 + ((((cc >> 2) ^ (R & 7)) << 2) | (cc & 3))] =
                        acc[mi][ni][r2] + bv;
                }
        }
        __syncthreads();
        float* outp = (float*)Cv;
#pragma unroll
        for (int p = 0; p < 8; ++p) {
            const int R   = (tid >> 4) + p * 16;
            const int chn = tid & 15;
            const f32x4 v = *(const f32x4*)&Cl[R * 64 + ((chn ^ (R & 7)) << 2)];
            *(f32x4*)&outp[(m0 + R) * (size_t)N + n0 + chn * 4] = v;
        }
    } else {
        // bf16 tile 128 x BN(=128): 32 KB = the whole arena.
        __bf16* Cl = (__bf16*)smem;
        const bool ahalf = (EPI == 2) && (n0 < 1024);   // block-uniform
#pragma unroll
        for (int ni = 0; ni < NI; ++ni) {
            const int cc = wn + ni * 16 + ec;
            const float bv = bias ? bias[n0 + cc] : 0.f;
#pragma unroll
            for (int mi = 0; mi < 4; ++mi)
#pragma unroll
                for (int r2 = 0; r2 < 4; ++r2) {
                    const int R = wm + mi * 16 + er + r2;
                    float v = acc[mi][ni][r2] + bv;
                    if (EPI == 2 && ahalf) v = gelu_tanh(v);
                    Cl[R * 128 + ((((cc >> 3) ^ (R & 7)) << 3) | (cc & 7))] = f2b(v);
                }
        }
        __syncthreads();
#pragma unroll
        for (int p = 0; p < 8; ++p) {
            const int R   = (tid >> 4) + p * 16;
            const int chn = tid & 15;
            const bf16x8 v = *(const bf16x8*)&Cl[R * 128 + ((chn ^ (R & 7)) << 3)];
            if (EPI == 1) {
                *(bf16x8*)((__bf16*)Cv + (m0 + R) * (size_t)N + n0 + chn * 8) = v;
            } else if (n0 < 1024) {
                *(bf16x8*)((__bf16*)Cv + (m0 + R) * 1024 + n0 + chn * 8) = v;
            } else {
                *(bf16x8*)((__bf16*)D2 + (m0 + R + 3) * 1024 + (n0 - 1024) + chn * 8) = v;
            }
        }
    }
}

// ---------------------------------------------------------------------------
// Conv, 64 MFMA/wave per barrier-pair, 2 blocks/CU:
//   bc[t,o] = sum_s sum_i W[o][s*1024+i] * bbp[t+s][i]
// Per kc (32 iters):
//  - B: ALL 4 shift tiles (4 x 128x32 = 32KB) double-buffered, staged at the
//    top of the previous iter (8 cp16/thread), counted vmcnt(8).
//  - A: 132-row halo (8.45KB) single-buffered, staged right after the
//    post-compute barrier (provably free there); covered by the next iter's
//    vmcnt(8) (its 2-3 loads are older than the 8 in-flight B loads).
//  - compute: 4 shifts x 16 MFMA, disjoint LDS regions, NO barriers between
//    shifts; plain C++ ds_reads (compiler's fine-grained lgkmcnt).
// LDS = 8448 + 2*32768 = 73984B -> 2 blocks/CU.
// ---------------------------------------------------------------------------
__global__ __launch_bounds__(256, 2)
void conv_mfma(const __hip_bfloat16* __restrict__ bbp,
               const __hip_bfloat16* __restrict__ W,
               __hip_bfloat16* __restrict__ C)
{
    __shared__ __align__(16) unsigned char smem[73984];
    __bf16* Ah = (__bf16*)smem;             // [132*32] halo, single-buffered
    __bf16* Bt = (__bf16*)(smem + 8448);    // [2][4][128*32] shift tiles

    const int tid  = threadIdx.x;
    const int lane = tid & 63;
    const int wave = tid >> 6;
    const size_t m0 = (size_t)blockIdx.x * 128;
    const int    n0 = blockIdx.y * 128;
    const int wm = (wave >> 1) * 64;
    const int wn = (wave & 1) * 64;

    f32x4 acc[4][4];
#pragma unroll
    for (int i = 0; i < 4; ++i)
#pragma unroll
        for (int j = 0; j < 4; ++j)
            acc[i][j] = f32x4{0.f, 0.f, 0.f, 0.f};

    const int frow = lane & 15;
    const int fq   = lane >> 4;

    auto stageA = [&](int kc) {             // 132 rows x 4 chunks = 528 chunks
#pragma unroll
        for (int q = 0; q < 2; ++q) {
            const int lin = q * 256 + tid;
            const int rr  = lin >> 2;
            const int gc  = (lin & 3) ^ ((rr >> 1) & 3);
            cp16_g2l(bbp + (m0 + rr) * 1024 + kc + gc * 8, Ah + lin * 8);
        }
        if (tid < 16) {
            const int lin = 512 + tid;
            const int rr  = lin >> 2;
            const int gc  = (lin & 3) ^ ((rr >> 1) & 3);
            cp16_g2l(bbp + (m0 + rr) * 1024 + kc + gc * 8, Ah + lin * 8);
        }
    };
    auto stageB = [&](int buf, int kc) {    // 4 shift tiles x 512 chunks
#pragma unroll
        for (int s = 0; s < 4; ++s)
#pragma unroll
            for (int q = 0; q < 2; ++q) {
                const int lin = q * 256 + tid;
                const int rr  = lin >> 2;
                const int gc  = (lin & 3) ^ ((rr >> 1) & 3);
                cp16_g2l(W + (size_t)(n0 + rr) * 4096 + s * 1024 + kc + gc * 8,
                         Bt + buf * 16384 + s * 4096 + lin * 8);
            }
    };

    stageA(0);
    stageB(0, 0);
    int bcur = 0;
    for (int t = 0; t < 32; ++t) {
        if (t + 1 < 32) {
            stageB(bcur ^ 1, (t + 1) * 32);
            // leave exactly the 8 just-issued B loads in flight; everything
            // older (this kc's B + halo) must be complete.
            asm volatile("s_waitcnt vmcnt(8)" ::: "memory");
        } else {
            asm volatile("s_waitcnt vmcnt(0)" ::: "memory");
        }
        __builtin_amdgcn_sched_barrier(0);
        __builtin_amdgcn_s_barrier();          // halo + B[bcur] staged
        __builtin_amdgcn_sched_barrier(0);

        __builtin_amdgcn_s_setprio(1);
#pragma unroll
        for (int s = 0; s < 4; ++s) {
            bf16x8 af[4], bfr[4];
#pragma unroll
            for (int mi = 0; mi < 4; ++mi) {
                const int R = wm + mi * 16 + frow + s;       // shifted halo row
                af[mi] = *(const bf16x8*)&Ah[R * 32 + ((fq ^ ((R >> 1) & 3)) * 8)];
            }
#pragma unroll
            for (int ni = 0; ni < 4; ++ni) {
                const int R = wn + ni * 16 + frow;
                bfr[ni] = *(const bf16x8*)&Bt[bcur * 16384 + s * 4096 + R * 32 +
                                              ((fq ^ ((R >> 1) & 3)) * 8)];
            }
#pragma unroll
            for (int mi = 0; mi < 4; ++mi)
#pragma unroll
                for (int ni = 0; ni < 4; ++ni)
                    acc[mi][ni] = __builtin_amdgcn_mfma_f32_16x16x32_bf16(
                        af[mi], bfr[ni], acc[mi][ni], 0, 0, 0);
        }
        __builtin_amdgcn_s_setprio(0);
        __builtin_amdgcn_sched_barrier(0);
        __builtin_amdgcn_s_barrier();          // halo + B[bcur] free
        __builtin_amdgcn_sched_barrier(0);
        if (t + 1 < 32) stageA((t + 1) * 32);  // halo prefetch into freed buffer
        bcur ^= 1;
    }

    // ---- epilogue: bf16 tile 128x128 via swizzled LDS, coalesced stores.
    __syncthreads();
    const int er = fq * 4;
    const int ec = frow;
    __bf16* Cl = (__bf16*)smem;
#pragma unroll
    for (int ni = 0; ni < 4; ++ni) {
        const int cc = wn + ni * 16 + ec;
#pragma unroll
        for (int mi = 0; mi < 4; ++mi)
#pragma unroll
            for (int r2 = 0; r2 < 4; ++r2) {
                const int R = wm + mi * 16 + er + r2;
                Cl[R * 128 + ((((cc >> 3) ^ (R & 7)) << 3) | (cc & 7))] =
                    f2b(acc[mi][ni][r2]);
            }
    }
    __syncthreads();
#pragma unroll
    for (int p = 0; p < 8; ++p) {
        const int R   = (tid >> 4) + p * 16;
        const int chn = tid & 15;
        const bf16x8 v = *(const bf16x8*)&Cl[R * 128 + ((chn ^ (R & 7)) << 3)];
        *(bf16x8*)((__bf16*)C + (m0 + R) * 1024 + n0 + chn * 8) = v;
    }
}

// One prep kernel: xb, w1b, w_rgb, w_outb conversions + conv repack + bbp pad zero.
#define PREP_X   6291456            // 8192*768
#define PREP_W1  (PREP_X + 1572864) // + 2048*768
#define PREP_WRG (PREP_W1 + 2097152)// + 2048*1024
#define PREP_WO  (PREP_WRG + 786432)// + 768*1024
#define PREP_CW  (PREP_WO + 4194304)// + 1024*4096
#define PREP_TOT (PREP_CW + 3072)   // + pad rows
__global__ void prep_kernel(const float* __restrict__ x, const float* __restrict__ w1,
                            const float* __restrict__ w_rg, const float* __restrict__ w_out,
                            const float* __restrict__ conv_w,
                            __hip_bfloat16* __restrict__ xb, __hip_bfloat16* __restrict__ w1b,
                            __hip_bfloat16* __restrict__ w_rgb, __hip_bfloat16* __restrict__ w_outb,
                            __hip_bfloat16* __restrict__ wbigb, __hip_bfloat16* __restrict__ bbp)
{
    const int idx = blockIdx.x * 256 + threadIdx.x;
    if (idx < PREP_X) {
        xb[idx] = __float2bfloat16(x[idx]);
    } else if (idx < PREP_W1) {
        const int i = idx - PREP_X;  w1b[i] = __float2bfloat16(w1[i]);
    } else if (idx < PREP_WRG) {
        const int i = idx - PREP_W1; w_rgb[i] = __float2bfloat16(w_rg[i]);
    } else if (idx < PREP_WO) {
        const int i = idx - PREP_WRG; w_outb[i] = __float2bfloat16(w_out[i]);
    } else if (idx < PREP_CW) {
        const int n = idx - PREP_WO;
        const int o = n >> 12, r = n & 4095, k = r >> 10, i = r & 1023;
        wbigb[n] = __float2bfloat16(conv_w[o * 4096 + i * 4 + k]);
    } else {
        bbp[idx - PREP_CW] = __float2bfloat16(0.f);
    }
}

// Gates recomputed inline from g_pre (T x 2048 bf16) + bc (bf16):
__global__ void scan_pass1(const __hip_bfloat16* __restrict__ gp,
                           const __hip_bfloat16* __restrict__ bc,
                           const float* __restrict__ Lambda,
                           float* __restrict__ ch, float* __restrict__ ca)
{
    const int c = blockIdx.y * 256 + threadIdx.x;
    const int j = blockIdx.x;
    const float cl = -8.f * log1pf(expf(Lambda[c]));
    float h = 0.f, ap = 1.f;
    const int t0 = j * CL;
    for (int tt = 0; tt < CL; ++tt) {
        const int t = t0 + tt;
        const long gi = (long)t * 2048 + c;
        const float ig = 1.f / (1.f + expf(-__bfloat162float(gp[gi])));
        const float rg = 1.f / (1.f + expf(-__bfloat162float(gp[gi + 1024])));
        const float a  = expf(cl * rg);
        const float gx = sqrtf(fmaxf(0.f, 1.f - a * a)) * ig *
                         __bfloat162float(bc[(long)t * 1024 + c]);
        h  = fmaf(a, h, gx);
        ap *= a;
    }
    ch[j * 1024 + c] = h;
    ca[j * 1024 + c] = ap;
}

__global__ void scan_combine(float* __restrict__ ch, const float* __restrict__ ca)
{
    const int c = blockIdx.x * 256 + threadIdx.x;
    float carry = 0.f;
    for (int j = 0; j < NC; ++j) {
        const float hj = ch[j * 1024 + c];
        const float aj = ca[j * 1024 + c];
        ch[j * 1024 + c] = carry;
        carry = fmaf(aj, carry, hj);
    }
}

// Rescan with carry; z = ab * y -> bf16 (zb aliases bc: same-element RMW per thread).
__global__ void scan_pass2(const __hip_bfloat16* __restrict__ gp, const __hip_bfloat16* bc,
                           const float* __restrict__ Lambda,
                           const float* __restrict__ carry_in,
                           const __hip_bfloat16* __restrict__ ab,
                           __hip_bfloat16* zb)
{
    const int c = blockIdx.y * 256 + threadIdx.x;
    const int j = blockIdx.x;
    const float cl = -8.f * log1pf(expf(Lambda[c]));
    float h = carry_in[j * 1024 + c];
    const int t0 = j * CL;
    for (int tt = 0; tt < CL; ++tt) {
        const int t = t0 + tt;
        const long gi = (long)t * 2048 + c;
        const long bi = (long)t * 1024 + c;
        const float ig = 1.f / (1.f + expf(-__bfloat162float(gp[gi])));
        const float rg = 1.f / (1.f + expf(-__bfloat162float(gp[gi + 1024])));
        const float a  = expf(cl * rg);
        const float gx = sqrtf(fmaxf(0.f, 1.f - a * a)) * ig * __bfloat162float(bc[bi]);
        h = fmaf(a, h, gx);
        zb[bi] = __float2bfloat16(__bfloat162float(ab[bi]) * h);
    }
}

extern "C" void kernel_launch(void* const* d_in, const int* in_sizes, int n_in,
                              void* d_out, int out_size, void* d_ws, size_t ws_size,
                              hipStream_t stream)
{
    const float* x      = (const float*)d_in[0];
    const float* w1     = (const float*)d_in[1];
    const float* b1     = (const float*)d_in[2];
    const float* conv_w = (const float*)d_in[3];
    const float* w_rg   = (const float*)d_in[4];
    const float* b_rg   = (const float*)d_in[5];
    const float* w_out  = (const float*)d_in[6];
    const float* b_out  = (const float*)d_in[7];
    const float* Lambda = (const float*)d_in[8];
    float* out = (float*)d_out;
    (void)in_sizes; (void)n_in; (void)out_size; (void)ws_size;

    // ---- workspace layout (~110 MB) ----
    char* p = (char*)d_ws;
    auto alloc = [&](size_t bytes) { char* r = p; p += (bytes + 255) & ~255ULL; return r; };
    __hip_bfloat16* gpre  = (__hip_bfloat16*)alloc(8192ULL * 2048 * 2); // 32 MB
    __hip_bfloat16* ab    = (__hip_bfloat16*)alloc(8192ULL * 1024 * 2); // 16 MB
    __hip_bfloat16* bbp   = (__hip_bfloat16*)alloc(8200ULL * 1024 * 2); // 16.8 MB
    __hip_bfloat16* bcb   = (__hip_bfloat16*)alloc(8192ULL * 1024 * 2); // 16 MB (later zb)
    __hip_bfloat16* wbigb = (__hip_bfloat16*)alloc(1024ULL * 4096 * 2); // 8 MB
    __hip_bfloat16* xb    = (__hip_bfloat16*)alloc(8192ULL * 768 * 2);  // 12 MB
    __hip_bfloat16* w1b   = (__hip_bfloat16*)alloc(2048ULL * 768 * 2);  // 3 MB
    __hip_bfloat16* w_rgb = (__hip_bfloat16*)alloc(2048ULL * 1024 * 2); // 4 MB
    __hip_bfloat16* w_outb= (__hip_bfloat16*)alloc(768ULL * 1024 * 2);  // 1.5 MB
    float*          chv   = (float*)alloc(NC * 1024ULL * 4);
    float*          cav   = (float*)alloc(NC * 1024ULL * 4);
    __hip_bfloat16* zb    = bcb;   // overlay

    prep_kernel<<<PREP_TOT / 256, 256, 0, stream>>>(x, w1, w_rg, w_out, conv_w,
                                                    xb, w1b, w_rgb, w_outb, wbigb, bbp);

    // h = x @ w1.T + b1, fused split: ab = bf16(gelu), bbp = bf16 (rows +3)
    {
        dim3 grid(T_LEN / 128, 2048 / 128);
        gemm_mfma<128, 2, false><<<grid, 256, 0, stream>>>(xb, w1b, b1, ab, DM, DM, 2048, bbp);
    }

    // bc = causal conv (shift-reuse, 64 MFMA/barrier-pair) -> bf16
    {
        dim3 grid(T_LEN / 128, 1024 / 128);
        conv_mfma<<<grid, 256, 0, stream>>>(bbp, wbigb, bcb);
    }

    // g_pre = bc @ w_rg.T + b_rg -> bf16
    {
        dim3 grid(T_LEN / 128, 2048 / 128);
        gemm_mfma<128, 1, false><<<grid, 256, 0, stream>>>(bcb, w_rgb, b_rg, gpre, DR, DR, 2048, nullptr);
    }

    // chunked scan with fused gates; z = ab*y -> bf16 (overlays bcb)
    {
        dim3 gs(NC, DR / 256);
        scan_pass1<<<gs, 256, 0, stream>>>(gpre, bcb, Lambda, chv, cav);
        scan_combine<<<DR / 256, 256, 0, stream>>>(chv, cav);
        scan_pass2<<<gs, 256, 0, stream>>>(gpre, bcb, Lambda, chv, ab, zb);
    }

    // out = z @ w_out.T + b_out -> fp32
    {
        dim3 grid(T_LEN / 128, DM / 64);
        gemm_mfma<64, 0, false><<<grid, 256, 0, stream>>>(zb, w_outb, b_out, out, DR, DR, DM, nullptr);
    }
}

// Round 8
// 268.074 us; speedup vs baseline: 1.0165x; 1.0165x over previous
//
#include <hip/hip_runtime.h>
#include <hip/hip_bf16.h>
#include <stdint.h>

// ---------------------------------------------------------------------------
// RG-LRU block: T=8192, D_MODEL=768, D_RNN=1024, KW=4.
// Round 13: conv DS-pipe offload.  R7 accounting: conv iter ~5300cyc/CU =
// matrix 2065 (42% MfmaUtil) vs DS ~3700 (256 ds_read_b128 x 12cyc + staging
// writes) -> LDS port is the pacer.  W is L2-resident (1MB/y-panel) ->
// B-fragments now load DIRECTLY global->register from a fragment-major
// pre-transposed wbigb ([ntile][kcI][s][lane][16B], 1KB coalesced per wave
// load), register-double-buffered one full iter ahead (vmcnt(16)).  A-halo
// stays in LDS (dbuf, 16.9KB).  DS traffic 3700 -> ~1700 cyc/iter.
// Dense GEMMs / scans / prep(other segments) byte-identical to R7.
// ---------------------------------------------------------------------------

#define T_LEN 8192
#define DM 768
#define DR 1024
#define NC 128   // scan chunks
#define CL 64    // chunk length

typedef __bf16 bf16x8 __attribute__((ext_vector_type(8)));
typedef float  f32x4  __attribute__((ext_vector_type(4)));

#define AS1 __attribute__((address_space(1)))
#define AS3 __attribute__((address_space(3)))

__device__ __forceinline__ void cp16_g2l(const void* g, void* l) {
    __builtin_amdgcn_global_load_lds((const AS1 void*)g, (AS3 void*)l, 16, 0, 0);
}

__device__ __forceinline__ float gelu_tanh(float x) {
    const float inner = 0.7978845608028654f * (x + 0.044715f * x * x * x);
    return 0.5f * x * (1.f + tanhf(inner));
}

__device__ __forceinline__ __bf16 f2b(float v) {
    __hip_bfloat16 h = __float2bfloat16(v);
    return *reinterpret_cast<__bf16*>(&h);
}

// ---------------------------------------------------------------------------
// Pipelined dense GEMM: C[m,n] = sum_k A[m,k]*B[n,k] (+bias[n]).
// BM=128, BK=32, 256 threads (4 waves, 2Mx2N), 4 blocks/CU.  K % 32 == 0.
// LDS rows are 32 elements = 4 16B chunks; chunk slot s at row r holds global
// chunk s ^ ((r>>1) & 3)  -> bank-balanced wave64 ds_read_b128.
// EPI: 0 = fp32 +bias (BN=64); 1 = bf16 +bias; 2 = split (gelu->Cv / D2).
// Epilogue reuses the 32KB smem arena for coalesced 16B stores.
// (byte-identical to R7)
// ---------------------------------------------------------------------------
template<int BN, int EPI, bool SHIFT>
__global__ __launch_bounds__(256, 4)
void gemm_mfma(const __hip_bfloat16* __restrict__ A,
               const __hip_bfloat16* __restrict__ B,
               const float* __restrict__ bias,
               void* __restrict__ Cv,
               int K, int lda, int N,
               __hip_bfloat16* __restrict__ D2)
{
    constexpr int NI  = BN / 32;           // n-frags per wave (4 or 2)
    constexpr int BLD = (BN * 4) / 256;    // B cp16 per thread (2 or 1)
    constexpr int NLD = 2 + BLD;           // cp16 per thread per tile
    __shared__ __align__(16) unsigned char smem[32768];
    __bf16* Asb = (__bf16*)smem;            // [2][128*32]
    __bf16* Bsb = (__bf16*)(smem + 16384);  // [2][BN*32]

    const int tid  = threadIdx.x;
    const int lane = tid & 63;
    const int wave = tid >> 6;
    const size_t m0 = (size_t)blockIdx.x * 128;
    const int    n0 = blockIdx.y * BN;
    const int wm = (wave >> 1) * 64;
    const int wn = (wave & 1) * (BN / 2);

    f32x4 acc[4][NI];
#pragma unroll
    for (int i = 0; i < 4; ++i)
#pragma unroll
        for (int j = 0; j < NI; ++j)
            acc[i][j] = f32x4{0.f, 0.f, 0.f, 0.f};

    const int frow = lane & 15;
    const int fq   = lane >> 4;             // chunk index 0..3 within 32-wide row

    auto stage = [&](int buf, int k0) {
        // A tile: 128 rows x 4 chunks = 512 chunks
#pragma unroll
        for (int q = 0; q < 2; ++q) {
            const int lin = q * 256 + tid;
            const int rr  = lin >> 2;
            const int gc  = (lin & 3) ^ ((rr >> 1) & 3);
            const size_t ar = m0 + rr + (SHIFT ? (size_t)(k0 >> 10) : 0);
            const int    ac = SHIFT ? (k0 & 1023) : k0;
            cp16_g2l(A + ar * (size_t)lda + ac + gc * 8, Asb + buf * 4096 + lin * 8);
        }
        // B tile: BN rows x 4 chunks
#pragma unroll
        for (int q = 0; q < BLD; ++q) {
            const int lin = q * 256 + tid;
            const int rr  = lin >> 2;
            const int gc  = (lin & 3) ^ ((rr >> 1) & 3);
            cp16_g2l(B + (size_t)(n0 + rr) * K + k0 + gc * 8,
                     Bsb + buf * (BN * 32) + lin * 8);
        }
    };

    const int nt = K / 32;
    stage(0, 0);
    int cur = 0;
    for (int t = 0; t < nt; ++t) {
        if (t + 1 < nt) {
            stage(cur ^ 1, (t + 1) * 32);
            // wait only for tile t (the NLD loads just issued stay in flight)
            asm volatile("s_waitcnt vmcnt(%0)" :: "n"(NLD) : "memory");
        } else {
            asm volatile("s_waitcnt vmcnt(0)" ::: "memory");
        }
        __builtin_amdgcn_sched_barrier(0);
        __builtin_amdgcn_s_barrier();          // buf[cur] staged for all waves
        __builtin_amdgcn_sched_barrier(0);

        bf16x8 af[4], bfr[NI];
#pragma unroll
        for (int mi = 0; mi < 4; ++mi) {
            const int R = wm + mi * 16 + frow;
            af[mi] = *(const bf16x8*)&Asb[cur * 4096 + R * 32 + ((fq ^ ((R >> 1) & 3)) * 8)];
        }
#pragma unroll
        for (int ni = 0; ni < NI; ++ni) {
            const int R = wn + ni * 16 + frow;
            bfr[ni] = *(const bf16x8*)&Bsb[cur * (BN * 32) + R * 32 + ((fq ^ ((R >> 1) & 3)) * 8)];
        }
        asm volatile("s_waitcnt lgkmcnt(0)" ::: "memory");  // my reads serviced
        __builtin_amdgcn_sched_barrier(0);
        __builtin_amdgcn_s_barrier();          // buf[cur] free for overwrite
        __builtin_amdgcn_sched_barrier(0);

        __builtin_amdgcn_s_setprio(1);
#pragma unroll
        for (int mi = 0; mi < 4; ++mi)
#pragma unroll
            for (int ni = 0; ni < NI; ++ni)
                acc[mi][ni] = __builtin_amdgcn_mfma_f32_16x16x32_bf16(
                    af[mi], bfr[ni], acc[mi][ni], 0, 0, 0);
        __builtin_amdgcn_s_setprio(0);
        cur ^= 1;
    }

    // ---- epilogue: acc -> swizzled LDS -> coalesced 16B/lane global stores.
    // C/D frag layout: col = lane&15, row = (lane>>4)*4 + reg.
    __syncthreads();
    const int er = fq * 4;
    const int ec = frow;

    if (EPI == 0) {
        // fp32 tile 128 x BN(=64): 32 KB = the whole arena.
        float* Cl = (float*)smem;
#pragma unroll
        for (int ni = 0; ni < NI; ++ni) {
            const int cc = wn + ni * 16 + ec;
            const float bv = bias ? bias[n0 + cc] : 0.f;
#pragma unroll
            for (int mi = 0; mi < 4; ++mi)
#pragma unroll
                for (int r2 = 0; r2 < 4; ++r2) {
                    const int R = wm + mi * 16 + er + r2;
                    Cl[R * 64 + ((((cc >> 2) ^ (R & 7)) << 2) | (cc & 3))] =
                        acc[mi][ni][r2] + bv;
                }
        }
        __syncthreads();
        float* outp = (float*)Cv;
#pragma unroll
        for (int p = 0; p < 8; ++p) {
            const int R   = (tid >> 4) + p * 16;
            const int chn = tid & 15;
            const f32x4 v = *(const f32x4*)&Cl[R * 64 + ((chn ^ (R & 7)) << 2)];
            *(f32x4*)&outp[(m0 + R) * (size_t)N + n0 + chn * 4] = v;
        }
    } else {
        // bf16 tile 128 x BN(=128): 32 KB = the whole arena.
        __bf16* Cl = (__bf16*)smem;
        const bool ahalf = (EPI == 2) && (n0 < 1024);   // block-uniform
#pragma unroll
        for (int ni = 0; ni < NI; ++ni) {
            const int cc = wn + ni * 16 + ec;
            const float bv = bias ? bias[n0 + cc] : 0.f;
#pragma unroll
            for (int mi = 0; mi < 4; ++mi)
#pragma unroll
                for (int r2 = 0; r2 < 4; ++r2) {
                    const int R = wm + mi * 16 + er + r2;
                    float v = acc[mi][ni][r2] + bv;
                    if (EPI == 2 && ahalf) v = gelu_tanh(v);
                    Cl[R * 128 + ((((cc >> 3) ^ (R & 7)) << 3) | (cc & 7))] = f2b(v);
                }
        }
        __syncthreads();
#pragma unroll
        for (int p = 0; p < 8; ++p) {
            const int R   = (tid >> 4) + p * 16;
            const int chn = tid & 15;
            const bf16x8 v = *(const bf16x8*)&Cl[R * 128 + ((chn ^ (R & 7)) << 3)];
            if (EPI == 1) {
                *(bf16x8*)((__bf16*)Cv + (m0 + R) * (size_t)N + n0 + chn * 8) = v;
            } else if (n0 < 1024) {
                *(bf16x8*)((__bf16*)Cv + (m0 + R) * 1024 + n0 + chn * 8) = v;
            } else {
                *(bf16x8*)((__bf16*)D2 + (m0 + R + 3) * 1024 + (n0 - 1024) + chn * 8) = v;
            }
        }
    }
}

// ---------------------------------------------------------------------------
// Conv, B-frags global->register (no LDS for B):
//   bc[t,o] = sum_s sum_i W[o][s*1024+i] * bbp[t+s][i]
// WB layout (fragment-major, built by prep): frag (ntile, kcI, s) is a 1KB
// block [lane][16B]; lane(fq*16+frow) holds W[ntile*16+frow][s*1024+kcI*32+
// fq*8 .. +7].  Element offset = ntile*65536 + kcI*2048 + s*512 + lane*8.
// Per iter (kcI = t, 32 iters):
//  - loadB(next): 16 coalesced global_load_dwordx4 into the off regs
//    (reg dbuf bA/bB, even/odd unrolled -> static indexing), vmcnt(16).
//  - A: 132-row halo in LDS dbuf (2 x 8.45KB), staged post-barrier as R7.
//  - compute: 4 shifts x (4 ds_read af + 16 MFMA from regs).
// LDS arena 32KB (halo 16.9KB; epilogue reuses whole arena).  2 blocks/CU
// (VGPR-bound: ~128 frag regs + 64 acc).
// ---------------------------------------------------------------------------
__global__ __launch_bounds__(256, 2)
void conv_mfma(const __hip_bfloat16* __restrict__ bbp,
               const __hip_bfloat16* __restrict__ WB,
               __hip_bfloat16* __restrict__ C)
{
    __shared__ __align__(16) unsigned char smem[32768];
    __bf16* Ah = (__bf16*)smem;             // [2][132*32] halo dbuf (16.9KB)

    const int tid  = threadIdx.x;
    const int lane = tid & 63;
    const int wave = tid >> 6;
    const size_t m0 = (size_t)blockIdx.x * 128;
    const int    n0 = blockIdx.y * 128;
    const int wm = (wave >> 1) * 64;
    const int wn = (wave & 1) * 64;

    f32x4 acc[4][4];
#pragma unroll
    for (int i = 0; i < 4; ++i)
#pragma unroll
        for (int j = 0; j < 4; ++j)
            acc[i][j] = f32x4{0.f, 0.f, 0.f, 0.f};

    const int frow = lane & 15;
    const int fq   = lane >> 4;

    // per-lane base into the fragment-major W: ntile_base = (n0+wn)/16
    const __bf16* wbase = (const __bf16*)WB +
        ((size_t)((n0 + wn) >> 4) << 16) + (lane << 3);

    auto loadB = [&](bf16x8 (&b)[4][4], int t1) {
#pragma unroll
        for (int s = 0; s < 4; ++s)
#pragma unroll
            for (int ni = 0; ni < 4; ++ni)
                b[s][ni] = *(const bf16x8*)(wbase + ((size_t)ni << 16) +
                                            t1 * 2048 + s * 512);
    };
    auto stageA = [&](int abuf, int kc) {   // 132 rows x 4 chunks = 528 chunks
#pragma unroll
        for (int q = 0; q < 2; ++q) {
            const int lin = q * 256 + tid;
            const int rr  = lin >> 2;
            const int gc  = (lin & 3) ^ ((rr >> 1) & 3);
            cp16_g2l(bbp + (m0 + rr) * 1024 + kc + gc * 8, Ah + abuf * 4224 + lin * 8);
        }
        if (tid < 16) {
            const int lin = 512 + tid;
            const int rr  = lin >> 2;
            const int gc  = (lin & 3) ^ ((rr >> 1) & 3);
            cp16_g2l(bbp + (m0 + rr) * 1024 + kc + gc * 8, Ah + abuf * 4224 + lin * 8);
        }
    };

    bf16x8 bA[4][4], bB[4][4];
    stageA(0, 0);
    loadB(bA, 0);

    auto iter = [&](bf16x8 (&bCur)[4][4], bf16x8 (&bNxt)[4][4], int t) {
        if (t + 1 < 32) {
            loadB(bNxt, t + 1);
            // leave exactly the 16 just-issued frag loads in flight; everything
            // older (this iter's frags + halo) must be complete.
            asm volatile("s_waitcnt vmcnt(16)" ::: "memory");
        } else {
            asm volatile("s_waitcnt vmcnt(0)" ::: "memory");
        }
        __builtin_amdgcn_sched_barrier(0);
        __builtin_amdgcn_s_barrier();          // halo[t&1] staged for all waves
        __builtin_amdgcn_sched_barrier(0);

        const int ab = (t & 1) * 4224;
        __builtin_amdgcn_s_setprio(1);
#pragma unroll
        for (int s = 0; s < 4; ++s) {
            bf16x8 af[4];
#pragma unroll
            for (int mi = 0; mi < 4; ++mi) {
                const int R = wm + mi * 16 + frow + s;       // shifted halo row
                af[mi] = *(const bf16x8*)&Ah[ab + R * 32 + ((fq ^ ((R >> 1) & 3)) * 8)];
            }
#pragma unroll
            for (int mi = 0; mi < 4; ++mi)
#pragma unroll
                for (int ni = 0; ni < 4; ++ni)
                    acc[mi][ni] = __builtin_amdgcn_mfma_f32_16x16x32_bf16(
                        af[mi], bCur[s][ni], acc[mi][ni], 0, 0, 0);
        }
        __builtin_amdgcn_s_setprio(0);
        __builtin_amdgcn_sched_barrier(0);
        __builtin_amdgcn_s_barrier();          // halo[t&1] free for overwrite
        __builtin_amdgcn_sched_barrier(0);
        if (t + 1 < 32) stageA((t + 1) & 1, (t + 1) * 32);
    };

#pragma unroll 1
    for (int tp = 0; tp < 16; ++tp) {
        iter(bA, bB, 2 * tp);
        iter(bB, bA, 2 * tp + 1);
    }

    // ---- epilogue: bf16 tile 128x128 via swizzled LDS, coalesced stores.
    __syncthreads();
    const int er = fq * 4;
    const int ec = frow;
    __bf16* Cl = (__bf16*)smem;
#pragma unroll
    for (int ni = 0; ni < 4; ++ni) {
        const int cc = wn + ni * 16 + ec;
#pragma unroll
        for (int mi = 0; mi < 4; ++mi)
#pragma unroll
            for (int r2 = 0; r2 < 4; ++r2) {
                const int R = wm + mi * 16 + er + r2;
                Cl[R * 128 + ((((cc >> 3) ^ (R & 7)) << 3) | (cc & 7))] =
                    f2b(acc[mi][ni][r2]);
            }
    }
    __syncthreads();
#pragma unroll
    for (int p = 0; p < 8; ++p) {
        const int R   = (tid >> 4) + p * 16;
        const int chn = tid & 15;
        const bf16x8 v = *(const bf16x8*)&Cl[R * 128 + ((chn ^ (R & 7)) << 3)];
        *(bf16x8*)((__bf16*)C + (m0 + R) * 1024 + n0 + chn * 8) = v;
    }
}

// One prep kernel: xb, w1b, w_rgb, w_outb conversions + conv frag-repack +
// bbp pad zero.  Only the conv segment changed vs R7 (fragment-major WB).
#define PREP_X   6291456            // 8192*768
#define PREP_W1  (PREP_X + 1572864) // + 2048*768
#define PREP_WRG (PREP_W1 + 2097152)// + 2048*1024
#define PREP_WO  (PREP_WRG + 786432)// + 768*1024
#define PREP_CW  (PREP_WO + 4194304)// + 1024*4096
#define PREP_TOT (PREP_CW + 3072)   // + pad rows
__global__ void prep_kernel(const float* __restrict__ x, const float* __restrict__ w1,
                            const float* __restrict__ w_rg, const float* __restrict__ w_out,
                            const float* __restrict__ conv_w,
                            __hip_bfloat16* __restrict__ xb, __hip_bfloat16* __restrict__ w1b,
                            __hip_bfloat16* __restrict__ w_rgb, __hip_bfloat16* __restrict__ w_outb,
                            __hip_bfloat16* __restrict__ wbigb, __hip_bfloat16* __restrict__ bbp)
{
    const int idx = blockIdx.x * 256 + threadIdx.x;
    if (idx < PREP_X) {
        xb[idx] = __float2bfloat16(x[idx]);
    } else if (idx < PREP_W1) {
        const int i = idx - PREP_X;  w1b[i] = __float2bfloat16(w1[i]);
    } else if (idx < PREP_WRG) {
        const int i = idx - PREP_W1; w_rgb[i] = __float2bfloat16(w_rg[i]);
    } else if (idx < PREP_WO) {
        const int i = idx - PREP_WRG; w_outb[i] = __float2bfloat16(w_out[i]);
    } else if (idx < PREP_CW) {
        // fragment-major conv weights: WB[nt][kcI][s][lane][8 bf16]
        // value = W[nt*16+frow][s*1024 + kcI*32 + fq*8 + j0]
        //       = conv_w[(nt*16+frow)*4096 + (kcI*32+fq*8+j0)*4 + s]
        const int n    = idx - PREP_WO;
        const int nt   = n >> 16;
        const int r1   = n & 65535;
        const int kcI  = r1 >> 11;
        const int r2   = r1 & 2047;
        const int s    = r2 >> 9;
        const int r3   = r2 & 511;
        const int l    = r3 >> 3;
        const int j0   = r3 & 7;
        const int frow = l & 15, fq = l >> 4;
        const int o = nt * 16 + frow;
        const int i = kcI * 32 + fq * 8 + j0;
        wbigb[n] = __float2bfloat16(conv_w[o * 4096 + i * 4 + s]);
    } else {
        bbp[idx - PREP_CW] = __float2bfloat16(0.f);
    }
}

// Gates recomputed inline from g_pre (T x 2048 bf16) + bc (bf16):
__global__ void scan_pass1(const __hip_bfloat16* __restrict__ gp,
                           const __hip_bfloat16* __restrict__ bc,
                           const float* __restrict__ Lambda,
                           float* __restrict__ ch, float* __restrict__ ca)
{
    const int c = blockIdx.y * 256 + threadIdx.x;
    const int j = blockIdx.x;
    const float cl = -8.f * log1pf(expf(Lambda[c]));
    float h = 0.f, ap = 1.f;
    const int t0 = j * CL;
    for (int tt = 0; tt < CL; ++tt) {
        const int t = t0 + tt;
        const long gi = (long)t * 2048 + c;
        const float ig = 1.f / (1.f + expf(-__bfloat162float(gp[gi])));
        const float rg = 1.f / (1.f + expf(-__bfloat162float(gp[gi + 1024])));
        const float a  = expf(cl * rg);
        const float gx = sqrtf(fmaxf(0.f, 1.f - a * a)) * ig *
                         __bfloat162float(bc[(long)t * 1024 + c]);
        h  = fmaf(a, h, gx);
        ap *= a;
    }
    ch[j * 1024 + c] = h;
    ca[j * 1024 + c] = ap;
}

__global__ void scan_combine(float* __restrict__ ch, const float* __restrict__ ca)
{
    const int c = blockIdx.x * 256 + threadIdx.x;
    float carry = 0.f;
    for (int j = 0; j < NC; ++j) {
        const float hj = ch[j * 1024 + c];
        const float aj = ca[j * 1024 + c];
        ch[j * 1024 + c] = carry;
        carry = fmaf(aj, carry, hj);
    }
}

// Rescan with carry; z = ab * y -> bf16 (zb aliases bc: same-element RMW per thread).
__global__ void scan_pass2(const __hip_bfloat16* __restrict__ gp, const __hip_bfloat16* bc,
                           const float* __restrict__ Lambda,
                           const float* __restrict__ carry_in,
                           const __hip_bfloat16* __restrict__ ab,
                           __hip_bfloat16* zb)
{
    const int c = blockIdx.y * 256 + threadIdx.x;
    const int j = blockIdx.x;
    const float cl = -8.f * log1pf(expf(Lambda[c]));
    float h = carry_in[j * 1024 + c];
    const int t0 = j * CL;
    for (int tt = 0; tt < CL; ++tt) {
        const int t = t0 + tt;
        const long gi = (long)t * 2048 + c;
        const long bi = (long)t * 1024 + c;
        const float ig = 1.f / (1.f + expf(-__bfloat162float(gp[gi])));
        const float rg = 1.f / (1.f + expf(-__bfloat162float(gp[gi + 1024])));
        const float a  = expf(cl * rg);
        const float gx = sqrtf(fmaxf(0.f, 1.f - a * a)) * ig * __bfloat162float(bc[bi]);
        h = fmaf(a, h, gx);
        zb[bi] = __float2bfloat16(__bfloat162float(ab[bi]) * h);
    }
}

extern "C" void kernel_launch(void* const* d_in, const int* in_sizes, int n_in,
                              void* d_out, int out_size, void* d_ws, size_t ws_size,
                              hipStream_t stream)
{
    const float* x      = (const float*)d_in[0];
    const float* w1     = (const float*)d_in[1];
    const float* b1     = (const float*)d_in[2];
    const float* conv_w = (const float*)d_in[3];
    const float* w_rg   = (const float*)d_in[4];
    const float* b_rg   = (const float*)d_in[5];
    const float* w_out  = (const float*)d_in[6];
    const float* b_out  = (const float*)d_in[7];
    const float* Lambda = (const float*)d_in[8];
    float* out = (float*)d_out;
    (void)in_sizes; (void)n_in; (void)out_size; (void)ws_size;

    // ---- workspace layout (~110 MB) ----
    char* p = (char*)d_ws;
    auto alloc = [&](size_t bytes) { char* r = p; p += (bytes + 255) & ~255ULL; return r; };
    __hip_bfloat16* gpre  = (__hip_bfloat16*)alloc(8192ULL * 2048 * 2); // 32 MB
    __hip_bfloat16* ab    = (__hip_bfloat16*)alloc(8192ULL * 1024 * 2); // 16 MB
    __hip_bfloat16* bbp   = (__hip_bfloat16*)alloc(8200ULL * 1024 * 2); // 16.8 MB
    __hip_bfloat16* bcb   = (__hip_bfloat16*)alloc(8192ULL * 1024 * 2); // 16 MB (later zb)
    __hip_bfloat16* wbigb = (__hip_bfloat16*)alloc(1024ULL * 4096 * 2); // 8 MB
    __hip_bfloat16* xb    = (__hip_bfloat16*)alloc(8192ULL * 768 * 2);  // 12 MB
    __hip_bfloat16* w1b   = (__hip_bfloat16*)alloc(2048ULL * 768 * 2);  // 3 MB
    __hip_bfloat16* w_rgb = (__hip_bfloat16*)alloc(2048ULL * 1024 * 2); // 4 MB
    __hip_bfloat16* w_outb= (__hip_bfloat16*)alloc(768ULL * 1024 * 2);  // 1.5 MB
    float*          chv   = (float*)alloc(NC * 1024ULL * 4);
    float*          cav   = (float*)alloc(NC * 1024ULL * 4);
    __hip_bfloat16* zb    = bcb;   // overlay

    prep_kernel<<<PREP_TOT / 256, 256, 0, stream>>>(x, w1, w_rg, w_out, conv_w,
                                                    xb, w1b, w_rgb, w_outb, wbigb, bbp);

    // h = x @ w1.T + b1, fused split: ab = bf16(gelu), bbp = bf16 (rows +3)
    {
        dim3 grid(T_LEN / 128, 2048 / 128);
        gemm_mfma<128, 2, false><<<grid, 256, 0, stream>>>(xb, w1b, b1, ab, DM, DM, 2048, bbp);
    }

    // bc = causal conv (B-frags global->reg from fragment-major WB) -> bf16
    {
        dim3 grid(T_LEN / 128, 1024 / 128);
        conv_mfma<<<grid, 256, 0, stream>>>(bbp, wbigb, bcb);
    }

    // g_pre = bc @ w_rg.T + b_rg -> bf16
    {
        dim3 grid(T_LEN / 128, 2048 / 128);
        gemm_mfma<128, 1, false><<<grid, 256, 0, stream>>>(bcb, w_rgb, b_rg, gpre, DR, DR, 2048, nullptr);
    }

    // chunked scan with fused gates; z = ab*y -> bf16 (overlays bcb)
    {
        dim3 gs(NC, DR / 256);
        scan_pass1<<<gs, 256, 0, stream>>>(gpre, bcb, Lambda, chv, cav);
        scan_combine<<<DR / 256, 256, 0, stream>>>(chv, cav);
        scan_pass2<<<gs, 256, 0, stream>>>(gpre, bcb, Lambda, chv, ab, zb);
    }

    // out = z @ w_out.T + b_out -> fp32
    {
        dim3 grid(T_LEN / 128, DM / 64);
        gemm_mfma<64, 0, false><<<grid, 256, 0, stream>>>(zb, w_outb, b_out, out, DR, DR, DM, nullptr);
    }
}

// Round 10
// 267.616 us; speedup vs baseline: 1.0182x; 1.0017x over previous
//
#include <hip/hip_runtime.h>
#include <hip/hip_bf16.h>
#include <stdint.h>

// ---------------------------------------------------------------------------
// RG-LRU block: T=8192, D_MODEL=768, D_RNN=1024, KW=4.
// Round 14b (R9 compile fix: cast WF to __bf16* before pointer arith).
// Port the verified conv structure (R8, ~1010 TF) to the dense GEMMs,
// which were still on the 16-MFMA/barrier cadence (~570 TF):
//  - per iter = 64 k-cols: A 128x64 tile -> LDS dbuf (2x16KB arena),
//    B frags global(L2)->registers from fragment-major repacked weights
//    (reg-dbuf one iter ahead), 32 MFMA/wave per barrier-pair,
//    counted vmcnt(4+2*NI).  launch_bounds(256,2).
//  - prep: w1/w_rg/w_out segments emit fragment-major layout
//    [ntile][kt][lane][8] (same byte counts as before).
//  - conv_mfma, scans, epilogues byte-identical to R8.
// ---------------------------------------------------------------------------

#define T_LEN 8192
#define DM 768
#define DR 1024
#define NC 128   // scan chunks
#define CL 64    // chunk length

typedef __bf16 bf16x8 __attribute__((ext_vector_type(8)));
typedef float  f32x4  __attribute__((ext_vector_type(4)));

#define AS1 __attribute__((address_space(1)))
#define AS3 __attribute__((address_space(3)))

__device__ __forceinline__ void cp16_g2l(const void* g, void* l) {
    __builtin_amdgcn_global_load_lds((const AS1 void*)g, (AS3 void*)l, 16, 0, 0);
}

__device__ __forceinline__ float gelu_tanh(float x) {
    const float inner = 0.7978845608028654f * (x + 0.044715f * x * x * x);
    return 0.5f * x * (1.f + tanhf(inner));
}

__device__ __forceinline__ __bf16 f2b(float v) {
    __hip_bfloat16 h = __float2bfloat16(v);
    return *reinterpret_cast<__bf16*>(&h);
}

// ---------------------------------------------------------------------------
// Dense GEMM, conv-R8 structure: C[m,n] = sum_k A[m,k]*B[n,k] (+bias[n]).
// BM=128, iter=64 k-cols, 256 threads (4 waves, 2Mx2N), 2 blocks/CU.
// A: LDS dbuf [2][128*64], 64-wide rows = 8 chunks, slot s at row r holds
//    global chunk s ^ (r&7) (R1-verified bank-balanced scheme).
// B: fragment-major WF [ntile][kt][lane][16B]; lane (fq*16+frow) of frag
//    (nt,kt) holds B[nt*16+frow][kt*32+fq*8 .. +7].  Loaded 1KB-coalesced
//    per wave straight to regs, reg-dbuf (even/odd unroll, static idx).
// Per iter: stageA(next) + loadB(next) -> vmcnt(4+2*NI) -> barrier ->
//           2 ksteps x (4 ds_read_b128 + 4*NI MFMA) -> barrier.  K%64==0.
// EPI: 0 = fp32 +bias (BN=64); 1 = bf16 +bias; 2 = split (gelu->Cv / D2).
// Epilogue reuses the 32KB arena for coalesced 16B stores (as R8).
// ---------------------------------------------------------------------------
template<int BN, int EPI>
__global__ __launch_bounds__(256, 2)
void gemm_mfma(const __hip_bfloat16* __restrict__ A,
               const __hip_bfloat16* __restrict__ WF,
               const float* __restrict__ bias,
               void* __restrict__ Cv,
               int K, int lda, int N,
               __hip_bfloat16* __restrict__ D2)
{
    constexpr int NI = BN / 32;            // n-frags per wave (4 or 2)
    constexpr int NV = 4 + 2 * NI;         // in-flight vmem after next-issue
    __shared__ __align__(16) unsigned char smem[32768];
    __bf16* Asb = (__bf16*)smem;           // [2][128*64]

    const int tid  = threadIdx.x;
    const int lane = tid & 63;
    const int wave = tid >> 6;
    const size_t m0 = (size_t)blockIdx.x * 128;
    const int    n0 = blockIdx.y * BN;
    const int wm = (wave >> 1) * 64;
    const int wn = (wave & 1) * (BN / 2);

    f32x4 acc[4][NI];
#pragma unroll
    for (int i = 0; i < 4; ++i)
#pragma unroll
        for (int j = 0; j < NI; ++j)
            acc[i][j] = f32x4{0.f, 0.f, 0.f, 0.f};

    const int frow = lane & 15;
    const int fq   = lane >> 4;
    const int NKT  = K >> 5;               // 32-col k-steps
    const int nt   = K >> 6;               // 64-col iterations

    // per-lane base into fragment-major weights: ntile_base = (n0+wn)/16
    const __bf16* wbase = (const __bf16*)WF +
        (((size_t)((n0 + wn) >> 4) * NKT) << 9) + (lane << 3);

    auto loadB = [&](bf16x8 (&b)[2][NI], int t1) {
#pragma unroll
        for (int ks = 0; ks < 2; ++ks)
#pragma unroll
            for (int ni = 0; ni < NI; ++ni)
                b[ks][ni] = *(const bf16x8*)(wbase +
                    (((size_t)(ni * NKT + 2 * t1 + ks)) << 9));
    };
    auto stageA = [&](int buf, int k0) {   // 128 rows x 8 chunks = 1024 chunks
#pragma unroll
        for (int q = 0; q < 4; ++q) {
            const int lin = q * 256 + tid;
            const int rr  = lin >> 3;
            const int gc  = (lin & 7) ^ (rr & 7);
            cp16_g2l(A + (m0 + rr) * (size_t)lda + k0 + gc * 8,
                     Asb + buf * 8192 + lin * 8);
        }
    };

    bf16x8 bA[2][NI], bB[2][NI];
    stageA(0, 0);
    loadB(bA, 0);

    auto iter = [&](bf16x8 (&bCur)[2][NI], bf16x8 (&bNxt)[2][NI], int t) {
        if (t + 1 < nt) {
            stageA((t + 1) & 1, (t + 1) * 64);
            loadB(bNxt, t + 1);
            // leave exactly the just-issued 4 cp16 + 2*NI frag loads in
            // flight; everything for tile t must be complete.
            asm volatile("s_waitcnt vmcnt(%0)" :: "n"(NV) : "memory");
        } else {
            asm volatile("s_waitcnt vmcnt(0)" ::: "memory");
        }
        __builtin_amdgcn_sched_barrier(0);
        __builtin_amdgcn_s_barrier();          // A[t&1] staged for all waves
        __builtin_amdgcn_sched_barrier(0);

        const int ab = (t & 1) * 8192;
        __builtin_amdgcn_s_setprio(1);
#pragma unroll
        for (int ks = 0; ks < 2; ++ks) {
            bf16x8 af[4];
#pragma unroll
            for (int mi = 0; mi < 4; ++mi) {
                const int R = wm + mi * 16 + frow;
                af[mi] = *(const bf16x8*)&Asb[ab + R * 64 +
                                              (((ks * 4 + fq) ^ (R & 7)) * 8)];
            }
#pragma unroll
            for (int mi = 0; mi < 4; ++mi)
#pragma unroll
                for (int ni = 0; ni < NI; ++ni)
                    acc[mi][ni] = __builtin_amdgcn_mfma_f32_16x16x32_bf16(
                        af[mi], bCur[ks][ni], acc[mi][ni], 0, 0, 0);
        }
        __builtin_amdgcn_s_setprio(0);
        __builtin_amdgcn_sched_barrier(0);
        __builtin_amdgcn_s_barrier();          // A[t&1] free for overwrite
        __builtin_amdgcn_sched_barrier(0);
    };

#pragma unroll 1
    for (int tp = 0; tp < nt / 2; ++tp) {
        iter(bA, bB, 2 * tp);
        iter(bB, bA, 2 * tp + 1);
    }

    // ---- epilogue: acc -> swizzled LDS -> coalesced 16B/lane global stores.
    // C/D frag layout: col = lane&15, row = (lane>>4)*4 + reg.  (as R8)
    __syncthreads();
    const int er = fq * 4;
    const int ec = frow;

    if (EPI == 0) {
        // fp32 tile 128 x BN(=64): 32 KB = the whole arena.
        float* Cl = (float*)smem;
#pragma unroll
        for (int ni = 0; ni < NI; ++ni) {
            const int cc = wn + ni * 16 + ec;
            const float bv = bias ? bias[n0 + cc] : 0.f;
#pragma unroll
            for (int mi = 0; mi < 4; ++mi)
#pragma unroll
                for (int r2 = 0; r2 < 4; ++r2) {
                    const int R = wm + mi * 16 + er + r2;
                    Cl[R * 64 + ((((cc >> 2) ^ (R & 7)) << 2) | (cc & 3))] =
                        acc[mi][ni][r2] + bv;
                }
        }
        __syncthreads();
        float* outp = (float*)Cv;
#pragma unroll
        for (int p = 0; p < 8; ++p) {
            const int R   = (tid >> 4) + p * 16;
            const int chn = tid & 15;
            const f32x4 v = *(const f32x4*)&Cl[R * 64 + ((chn ^ (R & 7)) << 2)];
            *(f32x4*)&outp[(m0 + R) * (size_t)N + n0 + chn * 4] = v;
        }
    } else {
        // bf16 tile 128 x BN(=128): 32 KB = the whole arena.
        __bf16* Cl = (__bf16*)smem;
        const bool ahalf = (EPI == 2) && (n0 < 1024);   // block-uniform
#pragma unroll
        for (int ni = 0; ni < NI; ++ni) {
            const int cc = wn + ni * 16 + ec;
            const float bv = bias ? bias[n0 + cc] : 0.f;
#pragma unroll
            for (int mi = 0; mi < 4; ++mi)
#pragma unroll
                for (int r2 = 0; r2 < 4; ++r2) {
                    const int R = wm + mi * 16 + er + r2;
                    float v = acc[mi][ni][r2] + bv;
                    if (EPI == 2 && ahalf) v = gelu_tanh(v);
                    Cl[R * 128 + ((((cc >> 3) ^ (R & 7)) << 3) | (cc & 7))] = f2b(v);
                }
        }
        __syncthreads();
#pragma unroll
        for (int p = 0; p < 8; ++p) {
            const int R   = (tid >> 4) + p * 16;
            const int chn = tid & 15;
            const bf16x8 v = *(const bf16x8*)&Cl[R * 128 + ((chn ^ (R & 7)) << 3)];
            if (EPI == 1) {
                *(bf16x8*)((__bf16*)Cv + (m0 + R) * (size_t)N + n0 + chn * 8) = v;
            } else if (n0 < 1024) {
                *(bf16x8*)((__bf16*)Cv + (m0 + R) * 1024 + n0 + chn * 8) = v;
            } else {
                *(bf16x8*)((__bf16*)D2 + (m0 + R + 3) * 1024 + (n0 - 1024) + chn * 8) = v;
            }
        }
    }
}

// ---------------------------------------------------------------------------
// Conv (byte-identical to R8): B-frags global->register, A-halo LDS dbuf,
// 64 MFMA/wave per barrier-pair, 2 blocks/CU.
// ---------------------------------------------------------------------------
__global__ __launch_bounds__(256, 2)
void conv_mfma(const __hip_bfloat16* __restrict__ bbp,
               const __hip_bfloat16* __restrict__ WB,
               __hip_bfloat16* __restrict__ C)
{
    __shared__ __align__(16) unsigned char smem[32768];
    __bf16* Ah = (__bf16*)smem;             // [2][132*32] halo dbuf (16.9KB)

    const int tid  = threadIdx.x;
    const int lane = tid & 63;
    const int wave = tid >> 6;
    const size_t m0 = (size_t)blockIdx.x * 128;
    const int    n0 = blockIdx.y * 128;
    const int wm = (wave >> 1) * 64;
    const int wn = (wave & 1) * 64;

    f32x4 acc[4][4];
#pragma unroll
    for (int i = 0; i < 4; ++i)
#pragma unroll
        for (int j = 0; j < 4; ++j)
            acc[i][j] = f32x4{0.f, 0.f, 0.f, 0.f};

    const int frow = lane & 15;
    const int fq   = lane >> 4;

    const __bf16* wbase = (const __bf16*)WB +
        ((size_t)((n0 + wn) >> 4) << 16) + (lane << 3);

    auto loadB = [&](bf16x8 (&b)[4][4], int t1) {
#pragma unroll
        for (int s = 0; s < 4; ++s)
#pragma unroll
            for (int ni = 0; ni < 4; ++ni)
                b[s][ni] = *(const bf16x8*)(wbase + ((size_t)ni << 16) +
                                            t1 * 2048 + s * 512);
    };
    auto stageA = [&](int abuf, int kc) {   // 132 rows x 4 chunks = 528 chunks
#pragma unroll
        for (int q = 0; q < 2; ++q) {
            const int lin = q * 256 + tid;
            const int rr  = lin >> 2;
            const int gc  = (lin & 3) ^ ((rr >> 1) & 3);
            cp16_g2l(bbp + (m0 + rr) * 1024 + kc + gc * 8, Ah + abuf * 4224 + lin * 8);
        }
        if (tid < 16) {
            const int lin = 512 + tid;
            const int rr  = lin >> 2;
            const int gc  = (lin & 3) ^ ((rr >> 1) & 3);
            cp16_g2l(bbp + (m0 + rr) * 1024 + kc + gc * 8, Ah + abuf * 4224 + lin * 8);
        }
    };

    bf16x8 bA[4][4], bB[4][4];
    stageA(0, 0);
    loadB(bA, 0);

    auto iter = [&](bf16x8 (&bCur)[4][4], bf16x8 (&bNxt)[4][4], int t) {
        if (t + 1 < 32) {
            loadB(bNxt, t + 1);
            asm volatile("s_waitcnt vmcnt(16)" ::: "memory");
        } else {
            asm volatile("s_waitcnt vmcnt(0)" ::: "memory");
        }
        __builtin_amdgcn_sched_barrier(0);
        __builtin_amdgcn_s_barrier();          // halo[t&1] staged for all waves
        __builtin_amdgcn_sched_barrier(0);

        const int ab = (t & 1) * 4224;
        __builtin_amdgcn_s_setprio(1);
#pragma unroll
        for (int s = 0; s < 4; ++s) {
            bf16x8 af[4];
#pragma unroll
            for (int mi = 0; mi < 4; ++mi) {
                const int R = wm + mi * 16 + frow + s;       // shifted halo row
                af[mi] = *(const bf16x8*)&Ah[ab + R * 32 + ((fq ^ ((R >> 1) & 3)) * 8)];
            }
#pragma unroll
            for (int mi = 0; mi < 4; ++mi)
#pragma unroll
                for (int ni = 0; ni < 4; ++ni)
                    acc[mi][ni] = __builtin_amdgcn_mfma_f32_16x16x32_bf16(
                        af[mi], bCur[s][ni], acc[mi][ni], 0, 0, 0);
        }
        __builtin_amdgcn_s_setprio(0);
        __builtin_amdgcn_sched_barrier(0);
        __builtin_amdgcn_s_barrier();          // halo[t&1] free for overwrite
        __builtin_amdgcn_sched_barrier(0);
        if (t + 1 < 32) stageA((t + 1) & 1, (t + 1) * 32);
    };

#pragma unroll 1
    for (int tp = 0; tp < 16; ++tp) {
        iter(bA, bB, 2 * tp);
        iter(bB, bA, 2 * tp + 1);
    }

    // ---- epilogue: bf16 tile 128x128 via swizzled LDS, coalesced stores.
    __syncthreads();
    const int er = fq * 4;
    const int ec = frow;
    __bf16* Cl = (__bf16*)smem;
#pragma unroll
    for (int ni = 0; ni < 4; ++ni) {
        const int cc = wn + ni * 16 + ec;
#pragma unroll
        for (int mi = 0; mi < 4; ++mi)
#pragma unroll
            for (int r2 = 0; r2 < 4; ++r2) {
                const int R = wm + mi * 16 + er + r2;
                Cl[R * 128 + ((((cc >> 3) ^ (R & 7)) << 3) | (cc & 7))] =
                    f2b(acc[mi][ni][r2]);
            }
    }
    __syncthreads();
#pragma unroll
    for (int p = 0; p < 8; ++p) {
        const int R   = (tid >> 4) + p * 16;
        const int chn = tid & 15;
        const bf16x8 v = *(const bf16x8*)&Cl[R * 128 + ((chn ^ (R & 7)) << 3)];
        *(bf16x8*)((__bf16*)C + (m0 + R) * 1024 + n0 + chn * 8) = v;
    }
}

// One prep kernel.  w1/w_rg/w_out segments write FRAGMENT-MAJOR layouts
// [ntile][kt][lane][8]: lane(fq*16+frow) of frag (nt,kt) holds
// W[nt*16+frow][kt*32+fq*8+j0].  conv segment (R8 layout) + bbp unchanged.
#define PREP_X   6291456            // 8192*768
#define PREP_W1  (PREP_X + 1572864) // + 2048*768
#define PREP_WRG (PREP_W1 + 2097152)// + 2048*1024
#define PREP_WO  (PREP_WRG + 786432)// + 768*1024
#define PREP_CW  (PREP_WO + 4194304)// + 1024*4096
#define PREP_TOT (PREP_CW + 3072)   // + pad rows
__global__ void prep_kernel(const float* __restrict__ x, const float* __restrict__ w1,
                            const float* __restrict__ w_rg, const float* __restrict__ w_out,
                            const float* __restrict__ conv_w,
                            __hip_bfloat16* __restrict__ xb, __hip_bfloat16* __restrict__ w1f,
                            __hip_bfloat16* __restrict__ w_rgf, __hip_bfloat16* __restrict__ w_outf,
                            __hip_bfloat16* __restrict__ wbigb, __hip_bfloat16* __restrict__ bbp)
{
    const int idx = blockIdx.x * 256 + threadIdx.x;
    if (idx < PREP_X) {
        xb[idx] = __float2bfloat16(x[idx]);
    } else if (idx < PREP_W1) {
        // w1f: K=768, NKT=24, ntile block = 24*512 = 12288 elements
        const int i  = idx - PREP_X;
        const int nti = i / 12288;
        const int r  = i % 12288;
        const int kt = r >> 9;
        const int r2 = r & 511;
        const int l  = r2 >> 3, j0 = r2 & 7;
        const int row = nti * 16 + (l & 15);
        const int col = kt * 32 + (l >> 4) * 8 + j0;
        w1f[i] = __float2bfloat16(w1[row * 768 + col]);
    } else if (idx < PREP_WRG) {
        // w_rgf: K=1024, NKT=32, ntile block = 16384 elements
        const int i  = idx - PREP_W1;
        const int nti = i >> 14;
        const int r  = i & 16383;
        const int kt = r >> 9;
        const int r2 = r & 511;
        const int l  = r2 >> 3, j0 = r2 & 7;
        const int row = nti * 16 + (l & 15);
        const int col = kt * 32 + (l >> 4) * 8 + j0;
        w_rgf[i] = __float2bfloat16(w_rg[row * 1024 + col]);
    } else if (idx < PREP_WO) {
        // w_outf: 768 rows, K=1024, NKT=32
        const int i  = idx - PREP_WRG;
        const int nti = i >> 14;
        const int r  = i & 16383;
        const int kt = r >> 9;
        const int r2 = r & 511;
        const int l  = r2 >> 3, j0 = r2 & 7;
        const int row = nti * 16 + (l & 15);
        const int col = kt * 32 + (l >> 4) * 8 + j0;
        w_outf[i] = __float2bfloat16(w_out[row * 1024 + col]);
    } else if (idx < PREP_CW) {
        // fragment-major conv weights: WB[nt][kcI][s][lane][8 bf16]
        const int n    = idx - PREP_WO;
        const int nti  = n >> 16;
        const int r1   = n & 65535;
        const int kcI  = r1 >> 11;
        const int r2   = r1 & 2047;
        const int s    = r2 >> 9;
        const int r3   = r2 & 511;
        const int l    = r3 >> 3;
        const int j0   = r3 & 7;
        const int frow = l & 15, fq = l >> 4;
        const int o = nti * 16 + frow;
        const int i = kcI * 32 + fq * 8 + j0;
        wbigb[n] = __float2bfloat16(conv_w[o * 4096 + i * 4 + s]);
    } else {
        bbp[idx - PREP_CW] = __float2bfloat16(0.f);
    }
}

// Gates recomputed inline from g_pre (T x 2048 bf16) + bc (bf16):
__global__ void scan_pass1(const __hip_bfloat16* __restrict__ gp,
                           const __hip_bfloat16* __restrict__ bc,
                           const float* __restrict__ Lambda,
                           float* __restrict__ ch, float* __restrict__ ca)
{
    const int c = blockIdx.y * 256 + threadIdx.x;
    const int j = blockIdx.x;
    const float cl = -8.f * log1pf(expf(Lambda[c]));
    float h = 0.f, ap = 1.f;
    const int t0 = j * CL;
    for (int tt = 0; tt < CL; ++tt) {
        const int t = t0 + tt;
        const long gi = (long)t * 2048 + c;
        const float ig = 1.f / (1.f + expf(-__bfloat162float(gp[gi])));
        const float rg = 1.f / (1.f + expf(-__bfloat162float(gp[gi + 1024])));
        const float a  = expf(cl * rg);
        const float gx = sqrtf(fmaxf(0.f, 1.f - a * a)) * ig *
                         __bfloat162float(bc[(long)t * 1024 + c]);
        h  = fmaf(a, h, gx);
        ap *= a;
    }
    ch[j * 1024 + c] = h;
    ca[j * 1024 + c] = ap;
}

__global__ void scan_combine(float* __restrict__ ch, const float* __restrict__ ca)
{
    const int c = blockIdx.x * 256 + threadIdx.x;
    float carry = 0.f;
    for (int j = 0; j < NC; ++j) {
        const float hj = ch[j * 1024 + c];
        const float aj = ca[j * 1024 + c];
        ch[j * 1024 + c] = carry;
        carry = fmaf(aj, carry, hj);
    }
}

// Rescan with carry; z = ab * y -> bf16 (zb aliases bc: same-element RMW per thread).
__global__ void scan_pass2(const __hip_bfloat16* __restrict__ gp, const __hip_bfloat16* bc,
                           const float* __restrict__ Lambda,
                           const float* __restrict__ carry_in,
                           const __hip_bfloat16* __restrict__ ab,
                           __hip_bfloat16* zb)
{
    const int c = blockIdx.y * 256 + threadIdx.x;
    const int j = blockIdx.x;
    const float cl = -8.f * log1pf(expf(Lambda[c]));
    float h = carry_in[j * 1024 + c];
    const int t0 = j * CL;
    for (int tt = 0; tt < CL; ++tt) {
        const int t = t0 + tt;
        const long gi = (long)t * 2048 + c;
        const long bi = (long)t * 1024 + c;
        const float ig = 1.f / (1.f + expf(-__bfloat162float(gp[gi])));
        const float rg = 1.f / (1.f + expf(-__bfloat162float(gp[gi + 1024])));
        const float a  = expf(cl * rg);
        const float gx = sqrtf(fmaxf(0.f, 1.f - a * a)) * ig * __bfloat162float(bc[bi]);
        h = fmaf(a, h, gx);
        zb[bi] = __float2bfloat16(__bfloat162float(ab[bi]) * h);
    }
}

extern "C" void kernel_launch(void* const* d_in, const int* in_sizes, int n_in,
                              void* d_out, int out_size, void* d_ws, size_t ws_size,
                              hipStream_t stream)
{
    const float* x      = (const float*)d_in[0];
    const float* w1     = (const float*)d_in[1];
    const float* b1     = (const float*)d_in[2];
    const float* conv_w = (const float*)d_in[3];
    const float* w_rg   = (const float*)d_in[4];
    const float* b_rg   = (const float*)d_in[5];
    const float* w_out  = (const float*)d_in[6];
    const float* b_out  = (const float*)d_in[7];
    const float* Lambda = (const float*)d_in[8];
    float* out = (float*)d_out;
    (void)in_sizes; (void)n_in; (void)out_size; (void)ws_size;

    // ---- workspace layout (~110 MB) ----
    char* p = (char*)d_ws;
    auto alloc = [&](size_t bytes) { char* r = p; p += (bytes + 255) & ~255ULL; return r; };
    __hip_bfloat16* gpre  = (__hip_bfloat16*)alloc(8192ULL * 2048 * 2); // 32 MB
    __hip_bfloat16* ab    = (__hip_bfloat16*)alloc(8192ULL * 1024 * 2); // 16 MB
    __hip_bfloat16* bbp   = (__hip_bfloat16*)alloc(8200ULL * 1024 * 2); // 16.8 MB
    __hip_bfloat16* bcb   = (__hip_bfloat16*)alloc(8192ULL * 1024 * 2); // 16 MB (later zb)
    __hip_bfloat16* wbigb = (__hip_bfloat16*)alloc(1024ULL * 4096 * 2); // 8 MB
    __hip_bfloat16* xb    = (__hip_bfloat16*)alloc(8192ULL * 768 * 2);  // 12 MB
    __hip_bfloat16* w1f   = (__hip_bfloat16*)alloc(2048ULL * 768 * 2);  // 3 MB (frag-major)
    __hip_bfloat16* w_rgf = (__hip_bfloat16*)alloc(2048ULL * 1024 * 2); // 4 MB (frag-major)
    __hip_bfloat16* w_outf= (__hip_bfloat16*)alloc(768ULL * 1024 * 2);  // 1.5 MB (frag-major)
    float*          chv   = (float*)alloc(NC * 1024ULL * 4);
    float*          cav   = (float*)alloc(NC * 1024ULL * 4);
    __hip_bfloat16* zb    = bcb;   // overlay

    prep_kernel<<<PREP_TOT / 256, 256, 0, stream>>>(x, w1, w_rg, w_out, conv_w,
                                                    xb, w1f, w_rgf, w_outf, wbigb, bbp);

    // h = x @ w1.T + b1, fused split: ab = bf16(gelu), bbp = bf16 (rows +3)
    {
        dim3 grid(T_LEN / 128, 2048 / 128);
        gemm_mfma<128, 2><<<grid, 256, 0, stream>>>(xb, w1f, b1, ab, DM, DM, 2048, bbp);
    }

    // bc = causal conv (B-frags global->reg from fragment-major WB) -> bf16
    {
        dim3 grid(T_LEN / 128, 1024 / 128);
        conv_mfma<<<grid, 256, 0, stream>>>(bbp, wbigb, bcb);
    }

    // g_pre = bc @ w_rg.T + b_rg -> bf16
    {
        dim3 grid(T_LEN / 128, 2048 / 128);
        gemm_mfma<128, 1><<<grid, 256, 0, stream>>>(bcb, w_rgf, b_rg, gpre, DR, DR, 2048, nullptr);
    }

    // chunked scan with fused gates; z = ab*y -> bf16 (overlays bcb)
    {
        dim3 gs(NC, DR / 256);
        scan_pass1<<<gs, 256, 0, stream>>>(gpre, bcb, Lambda, chv, cav);
        scan_combine<<<DR / 256, 256, 0, stream>>>(chv, cav);
        scan_pass2<<<gs, 256, 0, stream>>>(gpre, bcb, Lambda, chv, ab, zb);
    }

    // out = z @ w_out.T + b_out -> fp32
    {
        dim3 grid(T_LEN / 128, DM / 64);
        gemm_mfma<64, 0><<<grid, 256, 0, stream>>>(zb, w_outf, b_out, out, DR, DR, DM, nullptr);
    }
}